// Round 11
// baseline (207.513 us; speedup 1.0000x reference)
//
#include <hip/hip_runtime.h>
#include <stdint.h>

// ---------------------------------------------------------------------------
// GCN 2-layer encoder.  dinv[v] = 1/sqrt(1+indeg(v));
//   Agg(H)[v] = dinv[v] * ( sum_{(r->v)} dinv[r]*H[r] + dinv[v]*H[v] )
// GEMM outputs pre-scaled by dinv[row]; edge stream = u16 source ids in a
// dest-CSR padded to 8-edge multiples with sentinel src=n (H row n is zero).
// Agg kernels: wave split into row-segments (8 B/lane), 32-bit saddr
// addressing, v_dot2_f32_f16 accumulation (1 VALU per fp16 pair).
// Layer-2 GEMM (128->64) fused into layer-1 agg epilogue via LDS fp16 dot.
// CSR build = 2-level bucket sort, heavy atomics in LDS only.
// ---------------------------------------------------------------------------

typedef _Float16 h2v   __attribute__((ext_vector_type(2)));
typedef _Float16 h4v   __attribute__((ext_vector_type(4)));
typedef _Float16 f16x8 __attribute__((ext_vector_type(8)));
typedef float    f32x4 __attribute__((ext_vector_type(4)));

#if defined(__has_builtin)
#if __has_builtin(__builtin_amdgcn_fdot2)
#define HAVE_FDOT2 1
#endif
#endif

__device__ __forceinline__ float fdot2_acc(h2v a, h2v b, float c) {
#ifdef HAVE_FDOT2
    return __builtin_amdgcn_fdot2(a, b, c, false);
#else
    return c + (float)a.x * (float)b.x + (float)a.y * (float)b.y;
#endif
}
__device__ __forceinline__ h2v as_h2(uint32_t u) { return __builtin_bit_cast(h2v, u); }

// prep: zero bucket counters + sentinel rows; W1 -> fp16 transposed WT1;
// W2 -> fp16 pair-packed W2P[k2][f] = (W2[2k2][f], W2[2k2+1][f])
__global__ void k_prep(const float* __restrict__ W1, const float* __restrict__ W2,
                       _Float16* __restrict__ WT1, h2v* __restrict__ W2P,
                       uint32_t* __restrict__ bcnt,
                       _Float16* __restrict__ h1, _Float16* __restrict__ h2, int n) {
    int i = blockIdx.x * blockDim.x + threadIdx.x;   // 0..16383
    if (i < 256) bcnt[i] = 0u;
    if (i < 128) h1[(size_t)n * 128 + i] = (_Float16)0.f;
    if (i < 64)  h2[(size_t)n * 64  + i] = (_Float16)0.f;
    if (i < 128 * 128) {
        int f = i >> 7, k = i & 127;
        WT1[i] = (_Float16)W1[k * 128 + f];
    }
    if (i < 4096) {
        int k2 = i >> 6, f = i & 63;
        h2v pr;
        pr.x = (_Float16)W2[(2 * k2) * 64 + f];
        pr.y = (_Float16)W2[(2 * k2 + 1) * 64 + f];
        W2P[i] = pr;
    }
}

// coarse histogram: bucket = dest >> 8, LDS-aggregated
__global__ __launch_bounds__(256)
void k_bhist(const int* __restrict__ col, uint32_t* __restrict__ bcnt, int E) {
    __shared__ uint32_t h[256];
    const int t = threadIdx.x;
    h[t] = 0u; __syncthreads();
    const int base = blockIdx.x * 4096;
#pragma unroll
    for (int k = 0; k < 16; ++k) {
        int i = base + k * 256 + t;
        if (i < E) atomicAdd(&h[__builtin_nontemporal_load(&col[i]) >> 8], 1u);
    }
    __syncthreads();
    if (h[t]) atomicAdd(&bcnt[t], h[t]);
}

// one-WG exclusive scan of bucket counts -> boff, bfill
__global__ void k_bscan(const uint32_t* __restrict__ bcnt, uint32_t* __restrict__ boff,
                        uint32_t* __restrict__ bfill, int NB) {
    __shared__ uint32_t s[256];
    const int t = threadIdx.x;
    uint32_t v = (t < NB) ? bcnt[t] : 0u;
    s[t] = v; __syncthreads();
    for (int off = 1; off < 256; off <<= 1) {
        uint32_t u = (t >= off) ? s[t - off] : 0u;
        __syncthreads();
        s[t] += u;
        __syncthreads();
    }
    uint32_t ex = s[t] - v;
    if (t < NB) { boff[t] = ex; bfill[t] = ex; }
    if (t == NB - 1) boff[NB] = s[t];
}

// bin edges into bucket regions; per-WG chunk reservation -> coalescing writes
__global__ __launch_bounds__(256)
void k_bin(const int* __restrict__ row, const int* __restrict__ col,
           uint32_t* __restrict__ bfill, uint32_t* __restrict__ ebuf, int E) {
    __shared__ uint32_t hcnt[256], hbase[256];
    const int t = threadIdx.x;
    hcnt[t] = 0u; __syncthreads();
    const int base = blockIdx.x * 4096;
#pragma unroll
    for (int k = 0; k < 16; ++k) {
        int i = base + k * 256 + t;
        if (i < E) atomicAdd(&hcnt[__builtin_nontemporal_load(&col[i]) >> 8], 1u);
    }
    __syncthreads();
    hbase[t] = atomicAdd(&bfill[t], hcnt[t]);   // reserve contiguous chunk
    hcnt[t] = 0u;                                // reuse as local fill
    __syncthreads();
#pragma unroll
    for (int k = 0; k < 16; ++k) {
        int i = base + k * 256 + t;
        if (i < E) {
            int c = __builtin_nontemporal_load(&col[i]);
            int r = __builtin_nontemporal_load(&row[i]);
            int b = c >> 8;
            uint32_t slot = hbase[b] + atomicAdd(&hcnt[b], 1u);
            ebuf[slot] = (uint32_t)r | ((uint32_t)(c & 255) << 16);
        }
    }
}

// per-bucket finalize: LDS count + PADDED scan -> rps/rpe (8-aligned), dinv,
// esrc windows pre-filled with sentinel n, then LDS-atomic scatter.
__global__ __launch_bounds__(256)
void k_bucket(const uint32_t* __restrict__ boff, const uint32_t* __restrict__ ebuf,
              uint32_t* __restrict__ rps, uint32_t* __restrict__ rpe,
              float* __restrict__ dinv, uint16_t* __restrict__ esrc, int n) {
    __shared__ uint32_t lcnt[256], lscan[256], lbase[256], lfill[256];
    __shared__ uint32_t s_total;
    const int t = threadIdx.x;
    const int b = blockIdx.x;
    const int base_c = b << 8;
    const int nc = min(256, n - base_c);
    const uint32_t start = boff[b], end = boff[b + 1];
    const uint32_t pstart = (start + (uint32_t)b * 2048u + 7u) & ~7u;

    lcnt[t] = 0u; __syncthreads();
    for (uint32_t i = start + t; i < end; i += 256)
        atomicAdd(&lcnt[ebuf[i] >> 16], 1u);
    __syncthreads();

    const uint32_t v  = lcnt[t];
    const uint32_t pc = (v + 7u) & ~7u;          // padded count (mult of 8)
    lscan[t] = pc; __syncthreads();
    for (int off = 1; off < 256; off <<= 1) {    // inclusive scan of pc
        uint32_t u = (t >= off) ? lscan[t - off] : 0u;
        __syncthreads();
        lscan[t] += u;
        __syncthreads();
    }
    const uint32_t pex = lscan[t] - pc;          // padded exclusive
    if (t == 255) s_total = lscan[255];
    if (t < nc) {
        rps[base_c + t]  = pstart + pex;
        rpe[base_c + t]  = pstart + pex + pc;    // exact end (gap-safe)
        dinv[base_c + t] = rsqrtf((float)(v + 1u));
    }
    lbase[t] = pstart + pex;
    lfill[t] = 0u;
    __syncthreads();
    const uint32_t total = s_total;
    for (uint32_t i = t; i < total; i += 256)    // sentinel pre-fill
        esrc[pstart + i] = (uint16_t)n;
    __syncthreads();
    for (uint32_t i = start + t; i < end; i += 256) {
        uint32_t vv = ebuf[i];
        uint32_t cl = vv >> 16;
        uint32_t slot = lbase[cl] + atomicAdd(&lfill[cl], 1u);
        esrc[slot] = (uint16_t)(vv & 0xffffu);
    }
}

// ---- MFMA GEMM: h1s[r] = fp16(dinv[r] * (X[r] @ W1)), WT=[128][128] fp16 ----
template <int FOUT, typename XT>
__global__ __launch_bounds__(256)
void k_gemm_mfma(const XT* __restrict__ X, const _Float16* __restrict__ WT,
                 const float* __restrict__ dinv, _Float16* __restrict__ H, int n) {
    constexpr int K  = 128;
    constexpr int KP = K + 8;           // pad -> conflict-free ds_read_b128
    constexpr int NT = FOUT / 16;
    __shared__ _Float16 Wl[FOUT * KP];

    const int tid = threadIdx.x;
    for (int i = tid; i < FOUT * (K / 8); i += 256) {
        int f = i / (K / 8), kc = i % (K / 8);
        *reinterpret_cast<f16x8*>(&Wl[f * KP + kc * 8]) =
            *reinterpret_cast<const f16x8*>(&WT[f * K + kc * 8]);
    }
    __syncthreads();

    const int wid  = tid >> 6;
    const int lane = tid & 63;
    const int col  = lane & 15;
    const int krow = lane >> 4;
    const int node = blockIdx.x * 64 + wid * 16 + col;
    const int nld  = node < n ? node : n - 1;

    f32x4 acc[NT];
#pragma unroll
    for (int t = 0; t < NT; ++t) acc[t] = (f32x4){0.f, 0.f, 0.f, 0.f};

#pragma unroll
    for (int ks = 0; ks < 4; ++ks) {
        const int k0 = ks * 32 + krow * 8;
        f16x8 b;
        if constexpr (sizeof(XT) == 4) {
            float4 x0 = *reinterpret_cast<const float4*>(&X[(size_t)nld * K + k0]);
            float4 x1 = *reinterpret_cast<const float4*>(&X[(size_t)nld * K + k0 + 4]);
            b[0] = (_Float16)x0.x; b[1] = (_Float16)x0.y;
            b[2] = (_Float16)x0.z; b[3] = (_Float16)x0.w;
            b[4] = (_Float16)x1.x; b[5] = (_Float16)x1.y;
            b[6] = (_Float16)x1.z; b[7] = (_Float16)x1.w;
        } else {
            b = *reinterpret_cast<const f16x8*>(&X[(size_t)nld * K + k0]);
        }
#pragma unroll
        for (int t = 0; t < NT; ++t) {
            f16x8 a = *reinterpret_cast<const f16x8*>(&Wl[(t * 16 + col) * KP + k0]);
            acc[t] = __builtin_amdgcn_mfma_f32_16x16x32_f16(a, b, acc[t], 0, 0, 0);
        }
    }

    if (node < n) {
        const float dv = dinv[node];
#pragma unroll
        for (int t = 0; t < NT; ++t) {
            h4v hv;
            hv.x = (_Float16)(acc[t][0] * dv);
            hv.y = (_Float16)(acc[t][1] * dv);
            hv.z = (_Float16)(acc[t][2] * dv);
            hv.w = (_Float16)(acc[t][3] * dv);
            *reinterpret_cast<h4v*>(&H[(size_t)node * FOUT + t * 16 + krow * 4]) = hv;
        }
    }
}

// ---- fused agg128 + 128->64 GEMM.
// Wave = 1 node; halves of 32 lanes each cover the full 256 B row (8 B/lane,
// 4 features); half h processes edges ≡ h (mod 2).  fdot2 accumulation.
__global__ __launch_bounds__(256)
void k_aggmm(const _Float16* __restrict__ H, const uint32_t* __restrict__ rps,
             const uint32_t* __restrict__ rpe, const uint16_t* __restrict__ es,
             const float* __restrict__ dinv, const float* __restrict__ b1,
             const h2v* __restrict__ W2P, _Float16* __restrict__ h2out, int n) {
    __shared__ h2v      W2l[64 * 64];    // 16 KB pair-packed [k2][f]
    __shared__ _Float16 g1row[4][128];   // per-wave g1 (fp16)
    const int tid = threadIdx.x;
    for (int i = tid; i < 1024; i += 256)
        reinterpret_cast<uint4*>(W2l)[i] = reinterpret_cast<const uint4*>(W2P)[i];
    __syncthreads();

    const int wid = tid >> 6, lane = tid & 63;
    const int v = blockIdx.x * 4 + wid;
    if (v >= n) return;
    const uint32_t shift = (lane & 32) ? 16u : 0u;
    const uint32_t loff  = (uint32_t)(lane & 31) * 8u;   // byte off in row
    const char* Hb = (const char*)H;
    const h2v one0 = {(_Float16)1.f, (_Float16)0.f};
    const h2v zero1 = {(_Float16)0.f, (_Float16)1.f};

    int p = (int)rps[v];
    const int e = (int)rpe[v];           // (e - p) is a multiple of 8
    float a0 = 0.f, a1 = 0.f, a2 = 0.f, a3 = 0.f;

    for (; p + 8 <= e; p += 8) {
        const uint4 wa = *reinterpret_cast<const uint4*>(&es[p]);
        uint32_t dw[4] = {wa.x, wa.y, wa.z, wa.w};
#pragma unroll
        for (int j = 0; j < 4; ++j) {
            uint32_t id  = (dw[j] >> shift) & 0xffffu;   // v_bfe
            uint32_t off = (id << 8) + loff;             // v_lshl_add
            uint2 u = *reinterpret_cast<const uint2*>(Hb + off);
            h2v lo = as_h2(u.x), hi = as_h2(u.y);
            a0 = fdot2_acc(lo, one0,  a0);
            a1 = fdot2_acc(lo, zero1, a1);
            a2 = fdot2_acc(hi, one0,  a2);
            a3 = fdot2_acc(hi, zero1, a3);
        }
    }
    // combine halves
    a0 += __shfl_xor(a0, 32); a1 += __shfl_xor(a1, 32);
    a2 += __shfl_xor(a2, 32); a3 += __shfl_xor(a3, 32);

    // self row + layer-1 epilogue (duplicated on both halves, same values)
    {
        uint2 su = *reinterpret_cast<const uint2*>(Hb + ((uint32_t)v << 8) + loff);
        h2v lo = as_h2(su.x), hi = as_h2(su.y);
        a0 = fdot2_acc(lo, one0,  a0);
        a1 = fdot2_acc(lo, zero1, a1);
        a2 = fdot2_acc(hi, one0,  a2);
        a3 = fdot2_acc(hi, zero1, a3);
    }
    const float dv = dinv[v];
    const float4 bv = *reinterpret_cast<const float4*>(&b1[(lane & 31) * 4]);
    h4v gh;
    gh.x = (_Float16)fmaxf(fmaf(dv, a0, bv.x), 0.f);
    gh.y = (_Float16)fmaxf(fmaf(dv, a1, bv.y), 0.f);
    gh.z = (_Float16)fmaxf(fmaf(dv, a2, bv.z), 0.f);
    gh.w = (_Float16)fmaxf(fmaf(dv, a3, bv.w), 0.f);
    *reinterpret_cast<h4v*>(&g1row[wid][(lane & 31) * 4]) = gh;  // dup write ok

    // 128 -> 64 dot: lane = output feature; fdot2 over pair-packed k
    float acc = 0.f;
#pragma unroll
    for (int kb = 0; kb < 64; kb += 4) {
        uint4 gu = *reinterpret_cast<const uint4*>(&g1row[wid][kb * 2]);
        acc = fdot2_acc(W2l[(kb + 0) * 64 + lane], as_h2(gu.x), acc);
        acc = fdot2_acc(W2l[(kb + 1) * 64 + lane], as_h2(gu.y), acc);
        acc = fdot2_acc(W2l[(kb + 2) * 64 + lane], as_h2(gu.z), acc);
        acc = fdot2_acc(W2l[(kb + 3) * 64 + lane], as_h2(gu.w), acc);
    }
    h2out[(size_t)v * 64 + lane] = (_Float16)(dv * acc);
}

// ---- pull agg F=64: quads of 16 lanes cover the 128 B row (8 B/lane);
// quad q processes edges ≡ q (mod 4).  fdot2 accumulation, fp32 out.
__global__ __launch_bounds__(256)
void k_agg64(const _Float16* __restrict__ H, const uint32_t* __restrict__ rps,
             const uint32_t* __restrict__ rpe, const uint16_t* __restrict__ es,
             const float* __restrict__ dinv, const float* __restrict__ bias,
             float* __restrict__ out, int n) {
    int wave = (blockIdx.x * blockDim.x + threadIdx.x) >> 6;
    int lane = threadIdx.x & 63;
    if (wave >= n) return;
    const int v = wave;
    const bool seldw   = (lane & 32) != 0;
    const uint32_t shift = (lane & 16) ? 16u : 0u;
    const uint32_t loff  = (uint32_t)(lane & 15) * 8u;
    const char* Hb = (const char*)H;
    const h2v one0 = {(_Float16)1.f, (_Float16)0.f};
    const h2v zero1 = {(_Float16)0.f, (_Float16)1.f};

    int p = (int)rps[v];
    const int e = (int)rpe[v];
    float a0 = 0.f, a1 = 0.f, a2 = 0.f, a3 = 0.f;

    for (; p + 8 <= e; p += 8) {
        const uint4 wa = *reinterpret_cast<const uint4*>(&es[p]);
        uint32_t d0 = seldw ? wa.y : wa.x;      // edges p+0..3
        uint32_t d1 = seldw ? wa.w : wa.z;      // edges p+4..7
#pragma unroll
        for (int j = 0; j < 2; ++j) {
            uint32_t d = j ? d1 : d0;
            uint32_t id  = (d >> shift) & 0xffffu;
            uint32_t off = (id << 7) + loff;
            uint2 u = *reinterpret_cast<const uint2*>(Hb + off);
            h2v lo = as_h2(u.x), hi = as_h2(u.y);
            a0 = fdot2_acc(lo, one0,  a0);
            a1 = fdot2_acc(lo, zero1, a1);
            a2 = fdot2_acc(hi, one0,  a2);
            a3 = fdot2_acc(hi, zero1, a3);
        }
    }
    // combine the 4 quads
    a0 += __shfl_xor(a0, 16); a1 += __shfl_xor(a1, 16);
    a2 += __shfl_xor(a2, 16); a3 += __shfl_xor(a3, 16);
    a0 += __shfl_xor(a0, 32); a1 += __shfl_xor(a1, 32);
    a2 += __shfl_xor(a2, 32); a3 += __shfl_xor(a3, 32);

    if (lane < 16) {
        uint2 su = *reinterpret_cast<const uint2*>(Hb + ((uint32_t)v << 7) + loff);
        h2v lo = as_h2(su.x), hi = as_h2(su.y);
        a0 = fdot2_acc(lo, one0,  a0);
        a1 = fdot2_acc(lo, zero1, a1);
        a2 = fdot2_acc(hi, one0,  a2);
        a3 = fdot2_acc(hi, zero1, a3);
        const float dv = dinv[v];
        const float4 bv = *reinterpret_cast<const float4*>(&bias[lane * 4]);
        float4 o;
        o.x = fmaf(dv, a0, bv.x);
        o.y = fmaf(dv, a1, bv.y);
        o.z = fmaf(dv, a2, bv.z);
        o.w = fmaf(dv, a3, bv.w);
        *reinterpret_cast<float4*>(&out[(size_t)v * 64 + lane * 4]) = o;
    }
}

extern "C" void kernel_launch(void* const* d_in, const int* in_sizes, int n_in,
                              void* d_out, int out_size, void* d_ws, size_t ws_size,
                              hipStream_t stream) {
    const float* x  = (const float*)d_in[0];
    const int*   ei = (const int*)d_in[1];
    const float* W1 = (const float*)d_in[2];
    const float* b1 = (const float*)d_in[3];
    const float* W2 = (const float*)d_in[4];
    const float* b2 = (const float*)d_in[5];
    float* out = (float*)d_out;

    const int hidden = in_sizes[3];                 // 128
    const int fin    = in_sizes[2] / hidden;        // 128
    const int n      = in_sizes[0] / fin;           // 50000 (< 65536: u16 ids)
    const int E      = in_sizes[1] / 2;             // 800000
    const int* rowi = ei;                           // edge_index[0] = sources
    const int* coli = ei + E;                       // edge_index[1] = targets
    (void)n_in; (void)out_size; (void)ws_size;

    char* ws = (char*)d_ws;
    size_t off = 0;
    auto alloc = [&](size_t bytes) -> void* {
        off = (off + 255) & ~(size_t)255;
        void* p = ws + off;
        off += bytes;
        return p;
    };
    const int NB = (n + 255) >> 8;                   // 196 buckets
    uint32_t*  bcnt = (uint32_t*) alloc(256 * 4);
    uint32_t*  boff = (uint32_t*) alloc(257 * 4);
    uint32_t*  bfill= (uint32_t*) alloc(256 * 4);
    uint32_t*  rps  = (uint32_t*) alloc((size_t)n * 4);
    uint32_t*  rpe  = (uint32_t*) alloc((size_t)n * 4);
    float*     dinv = (float*)    alloc((size_t)n * 4);
    uint32_t*  ebuf = (uint32_t*) alloc((size_t)E * 4);
    uint16_t*  esrc = (uint16_t*) alloc(((size_t)E + (size_t)NB * 2048 + 4096) * 2);
    _Float16*  h1   = (_Float16*) alloc((size_t)(n + 1) * 128 * 2);
    _Float16*  h2   = (_Float16*) alloc((size_t)(n + 1) * 64 * 2);
    _Float16*  WT1  = (_Float16*) alloc(128 * 128 * 2);
    h2v*       W2P  = (h2v*)      alloc(64 * 64 * sizeof(h2v));

    const int NW = (E + 4095) >> 12;                 // 196 binning WGs

    k_prep  <<<64, 256, 0, stream>>>(W1, W2, WT1, W2P, bcnt, h1, h2, n);
    k_bhist <<<NW, 256, 0, stream>>>(coli, bcnt, E);
    k_bscan <<<1, 256, 0, stream>>>(bcnt, boff, bfill, NB);
    k_bin   <<<NW, 256, 0, stream>>>(rowi, coli, bfill, ebuf, E);
    k_bucket<<<NB, 256, 0, stream>>>(boff, ebuf, rps, rpe, dinv, esrc, n);

    const int gb = (n + 63) / 64;
    k_gemm_mfma<128, float><<<gb, 256, 0, stream>>>(x, WT1, dinv, h1, n);
    k_aggmm <<<(n + 3) / 4, 256, 0, stream>>>(h1, rps, rpe, esrc, dinv, b1, W2P, h2, n);
    k_agg64 <<<(n + 3) / 4, 256, 0, stream>>>(h2, rps, rpe, esrc, dinv, b2, out, n);
}

// Round 13
// 194.242 us; speedup vs baseline: 1.0683x; 1.0683x over previous
//
#include <hip/hip_runtime.h>
#include <stdint.h>

// ---------------------------------------------------------------------------
// GCN 2-layer encoder.  dinv[v] = 1/sqrt(1+indeg(v));
//   Agg(H)[v] = dinv[v] * ( sum_{(r->v)} dinv[r]*H[r] + dinv[v]*H[v] )
// GEMM outputs pre-scaled by dinv[row]; edge stream = u16 source ids in a
// dest-CSR padded to 16-edge multiples with sentinel src=n (H row n is zero)
// -> tail-free 16-edge loops, 8x8B gathers in flight per lane.
// k_aggmm: 4 nodes per wave, W2 staged once per WG (16 nodes), fused 128->64.
// CSR build = 2-level bucket sort, heavy atomics in LDS only.
// ---------------------------------------------------------------------------

typedef _Float16 h2v   __attribute__((ext_vector_type(2)));
typedef _Float16 h4v   __attribute__((ext_vector_type(4)));
typedef _Float16 f16x8 __attribute__((ext_vector_type(8)));
typedef float    f32x4 __attribute__((ext_vector_type(4)));

#if defined(__has_builtin)
#if __has_builtin(__builtin_amdgcn_fdot2)
#define HAVE_FDOT2 1
#endif
#endif

__device__ __forceinline__ float fdot2_acc(h2v a, h2v b, float c) {
#ifdef HAVE_FDOT2
    return __builtin_amdgcn_fdot2(a, b, c, false);
#else
    return c + (float)a.x * (float)b.x + (float)a.y * (float)b.y;
#endif
}
__device__ __forceinline__ h2v as_h2(uint32_t u) { return __builtin_bit_cast(h2v, u); }

// prep: zero bucket counters + sentinel rows; W1 -> fp16 transposed WT1;
// W2 -> fp16 pair-packed W2P[k2][f] = (W2[2k2][f], W2[2k2+1][f])
__global__ void k_prep(const float* __restrict__ W1, const float* __restrict__ W2,
                       _Float16* __restrict__ WT1, h2v* __restrict__ W2P,
                       uint32_t* __restrict__ bcnt,
                       _Float16* __restrict__ h1, _Float16* __restrict__ h2, int n) {
    int i = blockIdx.x * blockDim.x + threadIdx.x;   // 0..16383
    if (i < 256) bcnt[i] = 0u;
    if (i < 128) h1[(size_t)n * 128 + i] = (_Float16)0.f;
    if (i < 64)  h2[(size_t)n * 64  + i] = (_Float16)0.f;
    if (i < 128 * 128) {
        int f = i >> 7, k = i & 127;
        WT1[i] = (_Float16)W1[k * 128 + f];
    }
    if (i < 4096) {
        int k2 = i >> 6, f = i & 63;
        h2v pr;
        pr.x = (_Float16)W2[(2 * k2) * 64 + f];
        pr.y = (_Float16)W2[(2 * k2 + 1) * 64 + f];
        W2P[i] = pr;
    }
}

// coarse histogram: bucket = dest >> 8, LDS-aggregated
__global__ __launch_bounds__(256)
void k_bhist(const int* __restrict__ col, uint32_t* __restrict__ bcnt, int E) {
    __shared__ uint32_t h[256];
    const int t = threadIdx.x;
    h[t] = 0u; __syncthreads();
    const int base = blockIdx.x * 4096;
#pragma unroll
    for (int k = 0; k < 16; ++k) {
        int i = base + k * 256 + t;
        if (i < E) atomicAdd(&h[__builtin_nontemporal_load(&col[i]) >> 8], 1u);
    }
    __syncthreads();
    if (h[t]) atomicAdd(&bcnt[t], h[t]);
}

// one-WG exclusive scan of bucket counts -> boff, bfill
__global__ void k_bscan(const uint32_t* __restrict__ bcnt, uint32_t* __restrict__ boff,
                        uint32_t* __restrict__ bfill, int NB) {
    __shared__ uint32_t s[256];
    const int t = threadIdx.x;
    uint32_t v = (t < NB) ? bcnt[t] : 0u;
    s[t] = v; __syncthreads();
    for (int off = 1; off < 256; off <<= 1) {
        uint32_t u = (t >= off) ? s[t - off] : 0u;
        __syncthreads();
        s[t] += u;
        __syncthreads();
    }
    uint32_t ex = s[t] - v;
    if (t < NB) { boff[t] = ex; bfill[t] = ex; }
    if (t == NB - 1) boff[NB] = s[t];
}

// bin edges into bucket regions; per-WG chunk reservation -> coalescing writes
__global__ __launch_bounds__(256)
void k_bin(const int* __restrict__ row, const int* __restrict__ col,
           uint32_t* __restrict__ bfill, uint32_t* __restrict__ ebuf, int E) {
    __shared__ uint32_t hcnt[256], hbase[256];
    const int t = threadIdx.x;
    hcnt[t] = 0u; __syncthreads();
    const int base = blockIdx.x * 4096;
#pragma unroll
    for (int k = 0; k < 16; ++k) {
        int i = base + k * 256 + t;
        if (i < E) atomicAdd(&hcnt[__builtin_nontemporal_load(&col[i]) >> 8], 1u);
    }
    __syncthreads();
    hbase[t] = atomicAdd(&bfill[t], hcnt[t]);   // reserve contiguous chunk
    hcnt[t] = 0u;                                // reuse as local fill
    __syncthreads();
#pragma unroll
    for (int k = 0; k < 16; ++k) {
        int i = base + k * 256 + t;
        if (i < E) {
            int c = __builtin_nontemporal_load(&col[i]);
            int r = __builtin_nontemporal_load(&row[i]);
            int b = c >> 8;
            uint32_t slot = hbase[b] + atomicAdd(&hcnt[b], 1u);
            ebuf[slot] = (uint32_t)r | ((uint32_t)(c & 255) << 16);
        }
    }
}

// per-bucket finalize: LDS count + scan PADDED to 16 -> rps/rpe, dinv,
// esrc windows pre-filled with sentinel n, then LDS-atomic scatter.
__global__ __launch_bounds__(256)
void k_bucket(const uint32_t* __restrict__ boff, const uint32_t* __restrict__ ebuf,
              uint32_t* __restrict__ rps, uint32_t* __restrict__ rpe,
              float* __restrict__ dinv, uint16_t* __restrict__ esrc, int n) {
    __shared__ uint32_t lcnt[256], lscan[256], lbase[256], lfill[256];
    __shared__ uint32_t s_total;
    const int t = threadIdx.x;
    const int b = blockIdx.x;
    const int base_c = b << 8;
    const int nc = min(256, n - base_c);
    const uint32_t start = boff[b], end = boff[b + 1];
    const uint32_t pstart = (start + (uint32_t)b * 4096u + 15u) & ~15u;

    lcnt[t] = 0u; __syncthreads();
    for (uint32_t i = start + t; i < end; i += 256)
        atomicAdd(&lcnt[ebuf[i] >> 16], 1u);
    __syncthreads();

    const uint32_t v  = lcnt[t];
    const uint32_t pc = (v + 15u) & ~15u;        // padded count (mult of 16)
    lscan[t] = pc; __syncthreads();
    for (int off = 1; off < 256; off <<= 1) {    // inclusive scan of pc
        uint32_t u = (t >= off) ? lscan[t - off] : 0u;
        __syncthreads();
        lscan[t] += u;
        __syncthreads();
    }
    const uint32_t pex = lscan[t] - pc;          // padded exclusive
    if (t == 255) s_total = lscan[255];
    if (t < nc) {
        rps[base_c + t]  = pstart + pex;
        rpe[base_c + t]  = pstart + pex + pc;    // exact end (gap-safe)
        dinv[base_c + t] = rsqrtf((float)(v + 1u));
    }
    lbase[t] = pstart + pex;
    lfill[t] = 0u;
    __syncthreads();
    const uint32_t total = s_total;
    for (uint32_t i = t; i < total; i += 256)    // sentinel pre-fill
        esrc[pstart + i] = (uint16_t)n;
    __syncthreads();
    for (uint32_t i = start + t; i < end; i += 256) {
        uint32_t vv = ebuf[i];
        uint32_t cl = vv >> 16;
        uint32_t slot = lbase[cl] + atomicAdd(&lfill[cl], 1u);
        esrc[slot] = (uint16_t)(vv & 0xffffu);
    }
}

// ---- MFMA GEMM: h1s[r] = fp16(dinv[r] * (X[r] @ W1)), WT=[128][128] fp16 ----
template <int FOUT, typename XT>
__global__ __launch_bounds__(256)
void k_gemm_mfma(const XT* __restrict__ X, const _Float16* __restrict__ WT,
                 const float* __restrict__ dinv, _Float16* __restrict__ H, int n) {
    constexpr int K  = 128;
    constexpr int KP = K + 8;           // pad -> conflict-free ds_read_b128
    constexpr int NT = FOUT / 16;
    __shared__ _Float16 Wl[FOUT * KP];

    const int tid = threadIdx.x;
    for (int i = tid; i < FOUT * (K / 8); i += 256) {
        int f = i / (K / 8), kc = i % (K / 8);
        *reinterpret_cast<f16x8*>(&Wl[f * KP + kc * 8]) =
            *reinterpret_cast<const f16x8*>(&WT[f * K + kc * 8]);
    }
    __syncthreads();

    const int wid  = tid >> 6;
    const int lane = tid & 63;
    const int col  = lane & 15;
    const int krow = lane >> 4;
    const int node = blockIdx.x * 64 + wid * 16 + col;
    const int nld  = node < n ? node : n - 1;

    f32x4 acc[NT];
#pragma unroll
    for (int t = 0; t < NT; ++t) acc[t] = (f32x4){0.f, 0.f, 0.f, 0.f};

#pragma unroll
    for (int ks = 0; ks < 4; ++ks) {
        const int k0 = ks * 32 + krow * 8;
        f16x8 b;
        if constexpr (sizeof(XT) == 4) {
            float4 x0 = *reinterpret_cast<const float4*>(&X[(size_t)nld * K + k0]);
            float4 x1 = *reinterpret_cast<const float4*>(&X[(size_t)nld * K + k0 + 4]);
            b[0] = (_Float16)x0.x; b[1] = (_Float16)x0.y;
            b[2] = (_Float16)x0.z; b[3] = (_Float16)x0.w;
            b[4] = (_Float16)x1.x; b[5] = (_Float16)x1.y;
            b[6] = (_Float16)x1.z; b[7] = (_Float16)x1.w;
        } else {
            b = *reinterpret_cast<const f16x8*>(&X[(size_t)nld * K + k0]);
        }
#pragma unroll
        for (int t = 0; t < NT; ++t) {
            f16x8 a = *reinterpret_cast<const f16x8*>(&Wl[(t * 16 + col) * KP + k0]);
            acc[t] = __builtin_amdgcn_mfma_f32_16x16x32_f16(a, b, acc[t], 0, 0, 0);
        }
    }

    if (node < n) {
        const float dv = dinv[node];
#pragma unroll
        for (int t = 0; t < NT; ++t) {
            h4v hv;
            hv.x = (_Float16)(acc[t][0] * dv);
            hv.y = (_Float16)(acc[t][1] * dv);
            hv.z = (_Float16)(acc[t][2] * dv);
            hv.w = (_Float16)(acc[t][3] * dv);
            *reinterpret_cast<h4v*>(&H[(size_t)node * FOUT + t * 16 + krow * 4]) = hv;
        }
    }
}

// ---- fused agg128 + 128->64 GEMM.  4 nodes per wave; halves of 32 lanes
// cover the 256 B row (8 B/lane); half h takes u16 h of each dword.
// 16-edge iterations: 8 gathers in flight per lane.
__global__ __launch_bounds__(256)
void k_aggmm(const _Float16* __restrict__ H, const uint32_t* __restrict__ rps,
             const uint32_t* __restrict__ rpe, const uint16_t* __restrict__ es,
             const float* __restrict__ dinv, const float* __restrict__ b1,
             const h2v* __restrict__ W2P, _Float16* __restrict__ h2out, int n) {
    __shared__ h2v      W2l[64 * 64];    // 16 KB pair-packed [k2][f]
    __shared__ _Float16 g1row[4][128];   // per-wave g1 (fp16)
    const int tid = threadIdx.x;
    for (int i = tid; i < 1024; i += 256)
        reinterpret_cast<uint4*>(W2l)[i] = reinterpret_cast<const uint4*>(W2P)[i];
    __syncthreads();

    const int wid = tid >> 6, lane = tid & 63;
    const int v0 = blockIdx.x * 16 + wid * 4;
    if (v0 >= n) return;
    const uint32_t shift = (lane & 32) ? 16u : 0u;
    const uint32_t loff  = (uint32_t)(lane & 31) * 8u;   // byte off in row
    const char* Hb = (const char*)H;
    const h2v one0  = {(_Float16)1.f, (_Float16)0.f};
    const h2v zero1 = {(_Float16)0.f, (_Float16)1.f};
    const float4 bv = *reinterpret_cast<const float4*>(&b1[(lane & 31) * 4]);

    const uint4  rs4 = *reinterpret_cast<const uint4*>(&rps[v0]);
    const uint4  re4 = *reinterpret_cast<const uint4*>(&rpe[v0]);
    const float4 dv4 = *reinterpret_cast<const float4*>(&dinv[v0]);
    const uint32_t pss[4] = {rs4.x, rs4.y, rs4.z, rs4.w};
    const uint32_t pes[4] = {re4.x, re4.y, re4.z, re4.w};
    const float    dvs[4] = {dv4.x, dv4.y, dv4.z, dv4.w};

#pragma unroll
    for (int ni = 0; ni < 4; ++ni) {
        const int v = v0 + ni;
        if (v >= n) break;
        uint32_t p = pss[ni];
        const uint32_t e = pes[ni];      // (e - p) is a multiple of 16
        float a0 = 0.f, a1 = 0.f, a2 = 0.f, a3 = 0.f;

        for (; p < e; p += 16) {
            const uint4 wa = *reinterpret_cast<const uint4*>(&es[p]);
            const uint4 wb = *reinterpret_cast<const uint4*>(&es[p + 8]);
            uint32_t dw[8] = {wa.x, wa.y, wa.z, wa.w, wb.x, wb.y, wb.z, wb.w};
            uint2 u[8];
#pragma unroll
            for (int j = 0; j < 8; ++j) {
                uint32_t id = (dw[j] >> shift) & 0xffffu;
                u[j] = *reinterpret_cast<const uint2*>(Hb + (id << 8) + loff);
            }
#pragma unroll
            for (int j = 0; j < 8; ++j) {
                h2v lo = as_h2(u[j].x), hi = as_h2(u[j].y);
                a0 = fdot2_acc(lo, one0,  a0);
                a1 = fdot2_acc(lo, zero1, a1);
                a2 = fdot2_acc(hi, one0,  a2);
                a3 = fdot2_acc(hi, zero1, a3);
            }
        }
        // combine halves
        a0 += __shfl_xor(a0, 32); a1 += __shfl_xor(a1, 32);
        a2 += __shfl_xor(a2, 32); a3 += __shfl_xor(a3, 32);

        // self row + layer-1 epilogue (both halves, same values)
        {
            uint2 su = *reinterpret_cast<const uint2*>(Hb + ((uint32_t)v << 8) + loff);
            h2v lo = as_h2(su.x), hi = as_h2(su.y);
            a0 = fdot2_acc(lo, one0,  a0);
            a1 = fdot2_acc(lo, zero1, a1);
            a2 = fdot2_acc(hi, one0,  a2);
            a3 = fdot2_acc(hi, zero1, a3);
        }
        const float dv = dvs[ni];
        h4v gh;
        gh.x = (_Float16)fmaxf(fmaf(dv, a0, bv.x), 0.f);
        gh.y = (_Float16)fmaxf(fmaf(dv, a1, bv.y), 0.f);
        gh.z = (_Float16)fmaxf(fmaf(dv, a2, bv.z), 0.f);
        gh.w = (_Float16)fmaxf(fmaf(dv, a3, bv.w), 0.f);
        *reinterpret_cast<h4v*>(&g1row[wid][(lane & 31) * 4]) = gh;  // dup ok

        // 128 -> 64 dot, 4 independent fdot2 chains; lane = output feature
        float c0 = 0.f, c1 = 0.f, c2 = 0.f, c3 = 0.f;
#pragma unroll
        for (int kb = 0; kb < 64; kb += 4) {
            uint4 gu = *reinterpret_cast<const uint4*>(&g1row[wid][kb * 2]);
            c0 = fdot2_acc(W2l[(kb + 0) * 64 + lane], as_h2(gu.x), c0);
            c1 = fdot2_acc(W2l[(kb + 1) * 64 + lane], as_h2(gu.y), c1);
            c2 = fdot2_acc(W2l[(kb + 2) * 64 + lane], as_h2(gu.z), c2);
            c3 = fdot2_acc(W2l[(kb + 3) * 64 + lane], as_h2(gu.w), c3);
        }
        h2out[(size_t)v * 64 + lane] = (_Float16)(dv * ((c0 + c1) + (c2 + c3)));
    }
}

// ---- pull agg F=64: quads of 16 lanes cover the 128 B row (8 B/lane);
// quad q takes edges ≡ q (mod 4); 16-edge iters -> 4 gathers in flight.
__global__ __launch_bounds__(256)
void k_agg64(const _Float16* __restrict__ H, const uint32_t* __restrict__ rps,
             const uint32_t* __restrict__ rpe, const uint16_t* __restrict__ es,
             const float* __restrict__ dinv, const float* __restrict__ bias,
             float* __restrict__ out, int n) {
    int wave = (blockIdx.x * blockDim.x + threadIdx.x) >> 6;
    int lane = threadIdx.x & 63;
    if (wave >= n) return;
    const int v = wave;
    const int qi = (lane >> 4) & 3;
    const bool sely = (qi >> 1) != 0;
    const uint32_t shift = (qi & 1) ? 16u : 0u;
    const uint32_t loff  = (uint32_t)(lane & 15) * 8u;
    const char* Hb = (const char*)H;
    const h2v one0  = {(_Float16)1.f, (_Float16)0.f};
    const h2v zero1 = {(_Float16)0.f, (_Float16)1.f};

    uint32_t p = rps[v];
    const uint32_t e = rpe[v];
    float a0 = 0.f, a1 = 0.f, a2 = 0.f, a3 = 0.f;

    for (; p < e; p += 16) {
        const uint4 wa = *reinterpret_cast<const uint4*>(&es[p]);
        const uint4 wb = *reinterpret_cast<const uint4*>(&es[p + 8]);
        uint32_t d[4] = { sely ? wa.y : wa.x, sely ? wa.w : wa.z,
                          sely ? wb.y : wb.x, sely ? wb.w : wb.z };
        uint2 u[4];
#pragma unroll
        for (int j = 0; j < 4; ++j) {
            uint32_t id = (d[j] >> shift) & 0xffffu;
            u[j] = *reinterpret_cast<const uint2*>(Hb + (id << 7) + loff);
        }
#pragma unroll
        for (int j = 0; j < 4; ++j) {
            h2v lo = as_h2(u[j].x), hi = as_h2(u[j].y);
            a0 = fdot2_acc(lo, one0,  a0);
            a1 = fdot2_acc(lo, zero1, a1);
            a2 = fdot2_acc(hi, one0,  a2);
            a3 = fdot2_acc(hi, zero1, a3);
        }
    }
    // combine the 4 quads
    a0 += __shfl_xor(a0, 16); a1 += __shfl_xor(a1, 16);
    a2 += __shfl_xor(a2, 16); a3 += __shfl_xor(a3, 16);
    a0 += __shfl_xor(a0, 32); a1 += __shfl_xor(a1, 32);
    a2 += __shfl_xor(a2, 32); a3 += __shfl_xor(a3, 32);

    if (lane < 16) {
        uint2 su = *reinterpret_cast<const uint2*>(Hb + ((uint32_t)v << 7) + loff);
        h2v lo = as_h2(su.x), hi = as_h2(su.y);
        a0 = fdot2_acc(lo, one0,  a0);
        a1 = fdot2_acc(lo, zero1, a1);
        a2 = fdot2_acc(hi, one0,  a2);
        a3 = fdot2_acc(hi, zero1, a3);
        const float dv = dinv[v];
        const float4 bv = *reinterpret_cast<const float4*>(&bias[lane * 4]);
        float4 o;
        o.x = fmaf(dv, a0, bv.x);
        o.y = fmaf(dv, a1, bv.y);
        o.z = fmaf(dv, a2, bv.z);
        o.w = fmaf(dv, a3, bv.w);
        *reinterpret_cast<float4*>(&out[(size_t)v * 64 + lane * 4]) = o;
    }
}

extern "C" void kernel_launch(void* const* d_in, const int* in_sizes, int n_in,
                              void* d_out, int out_size, void* d_ws, size_t ws_size,
                              hipStream_t stream) {
    const float* x  = (const float*)d_in[0];
    const int*   ei = (const int*)d_in[1];
    const float* W1 = (const float*)d_in[2];
    const float* b1 = (const float*)d_in[3];
    const float* W2 = (const float*)d_in[4];
    const float* b2 = (const float*)d_in[5];
    float* out = (float*)d_out;

    const int hidden = in_sizes[3];                 // 128
    const int fin    = in_sizes[2] / hidden;        // 128
    const int n      = in_sizes[0] / fin;           // 50000 (< 65536: u16 ids)
    const int E      = in_sizes[1] / 2;             // 800000
    const int* rowi = ei;                           // edge_index[0] = sources
    const int* coli = ei + E;                       // edge_index[1] = targets
    (void)n_in; (void)out_size; (void)ws_size;

    char* ws = (char*)d_ws;
    size_t off = 0;
    auto alloc = [&](size_t bytes) -> void* {
        off = (off + 255) & ~(size_t)255;
        void* p = ws + off;
        off += bytes;
        return p;
    };
    const int NB = (n + 255) >> 8;                   // 196 buckets
    uint32_t*  bcnt = (uint32_t*) alloc(256 * 4);
    uint32_t*  boff = (uint32_t*) alloc(257 * 4);
    uint32_t*  bfill= (uint32_t*) alloc(256 * 4);
    uint32_t*  rps  = (uint32_t*) alloc((size_t)n * 4);
    uint32_t*  rpe  = (uint32_t*) alloc((size_t)n * 4);
    float*     dinv = (float*)    alloc((size_t)n * 4);
    uint32_t*  ebuf = (uint32_t*) alloc((size_t)E * 4);
    uint16_t*  esrc = (uint16_t*) alloc(((size_t)E + (size_t)NB * 4096 + 4096) * 2);
    _Float16*  h1   = (_Float16*) alloc((size_t)(n + 1) * 128 * 2);
    _Float16*  h2   = (_Float16*) alloc((size_t)(n + 1) * 64 * 2);
    _Float16*  WT1  = (_Float16*) alloc(128 * 128 * 2);
    h2v*       W2P  = (h2v*)      alloc(64 * 64 * sizeof(h2v));

    const int NW = (E + 4095) >> 12;                 // 196 binning WGs

    k_prep  <<<64, 256, 0, stream>>>(W1, W2, WT1, W2P, bcnt, h1, h2, n);
    k_bhist <<<NW, 256, 0, stream>>>(coli, bcnt, E);
    k_bscan <<<1, 256, 0, stream>>>(bcnt, boff, bfill, NB);
    k_bin   <<<NW, 256, 0, stream>>>(rowi, coli, bfill, ebuf, E);
    k_bucket<<<NB, 256, 0, stream>>>(boff, ebuf, rps, rpe, dinv, esrc, n);

    const int gb = (n + 63) / 64;
    k_gemm_mfma<128, float><<<gb, 256, 0, stream>>>(x, WT1, dinv, h1, n);
    k_aggmm <<<(n + 15) / 16, 256, 0, stream>>>(h1, rps, rpe, esrc, dinv, b1, W2P, h2, n);
    k_agg64 <<<(n + 3) / 4, 256, 0, stream>>>(h2, rps, rpe, esrc, dinv, b2, out, n);
}